// Round 7
// baseline (231.973 us; speedup 1.0000x reference)
//
#include <hip/hip_runtime.h>
#include <hip/hip_fp16.h>
#include <cstdio>
#include <cstdint>

#define HH 512
#define WW 512
#define CC 32
#define BB 2
#define NN 120000
#define HWPIX (HH*WW)
#define NPTS (BB*NN)          // 240000 occupied points (all pixels distinct: coors = permutation)
#define NPIX (BB*HWPIX)       // 524288 pixels (pixel-dense storage)
#define NBLK (NPIX/256)       // 2048 pixel windows

__device__ __forceinline__ void h8_to_f8(float4 raw, float* o) {
    const __half2* h = (const __half2*)&raw;
    #pragma unroll
    for (int i = 0; i < 4; ++i) {
        float2 f = __half22float2(h[i]);
        o[2 * i] = f.x; o[2 * i + 1] = f.y;
    }
}

// ---------------- prep: compose weights + vecs + zero flag map + zero counter ----------------
// M layout (floats): [0:1024) MqT, [1024:2048) MkT, [2048:3072) MvT, [3072:4096) owT
// V layout (floats): [0:32) bq'=W1@bq+in_b[:32], [32:64) bk'=W2@bk, [64:96) bv'=W3@bv,
// [96:128) PWy, [128:160) PWx, [160:192) pb3=W3@pos_b
__global__ __launch_bounds__(256) void prep(const float* __restrict__ wq, const float* __restrict__ wk,
                          const float* __restrict__ wv, const float* __restrict__ in_w,
                          const float* __restrict__ out_w,
                          const float* __restrict__ bq, const float* __restrict__ bk,
                          const float* __restrict__ bv, const float* __restrict__ in_b,
                          const float* __restrict__ pos_w, const float* __restrict__ pos_b,
                          float* __restrict__ M, float* __restrict__ V, int* __restrict__ fmap_i,
                          int* __restrict__ pcnt) {
    int blk = blockIdx.x;
    if (blk < 16) {
        int tid = blk * 256 + threadIdx.x;   // 0..4095
        int which = tid >> 10;
        int e = tid & 1023;
        int cp = e & 31;
        int j  = e >> 5;
        if (which < 3) {
            const float* w = (which == 0) ? wq : ((which == 1) ? wk : wv);
            const float* Wrow = in_w + (which * 32 + cp) * 32;
            float acc = 0.f;
            #pragma unroll
            for (int t = 0; t < 32; ++t) acc += Wrow[t] * w[t * 32 + j];
            M[which * 1024 + j * 32 + cp] = acc;
        } else {
            M[3 * 1024 + j * 32 + cp] = out_w[cp * 32 + j];
        }
    } else if (blk == 16) {
        int tid = threadIdx.x;
        if (tid < 32) {
            float a = 0.f, b = 0.f, c = 0.f;
            #pragma unroll
            for (int t = 0; t < 32; ++t) {
                a += in_w[tid * 32 + t] * bq[t];
                b += in_w[(32 + tid) * 32 + t] * bk[t];
                c += in_w[(64 + tid) * 32 + t] * bv[t];
            }
            V[tid]      = a + in_b[tid];
            V[32 + tid] = b;
            V[64 + tid] = c;
        } else if (tid < 128) {
            int grp = (tid - 32) >> 5;   // 0=PWy 1=PWx 2=pb3
            int cp  = tid & 31;
            float acc = 0.f;
            #pragma unroll
            for (int t = 0; t < 32; ++t) {
                float src = (grp == 0) ? pos_w[t * 2 + 0] : ((grp == 1) ? pos_w[t * 2 + 1] : pos_b[t]);
                acc += in_w[(64 + cp) * 32 + t] * src;
            }
            V[96 + grp * 32 + cp] = acc;
        } else if (tid == 128) {
            *pcnt = 0;
        }
    } else {
        // blocks 17..80: zero the 512 KB flag map (131072 ints; 64 blocks x 256 thr x 8 ints)
        int base = (blk - 17) * 2048 + threadIdx.x * 8;
        int4 z = {0, 0, 0, 0};
        *(int4*)(fmap_i + base)     = z;
        *(int4*)(fmap_i + base + 4) = z;
    }
}

// ---------------- stage1: point-parallel LN + fused q/k/v linears (pixel-dense out) ----------------
__global__ __launch_bounds__(256) void stage1(const float* __restrict__ feats,
                                              const int* __restrict__ coors,
                                              const float* __restrict__ ln_w,
                                              const float* __restrict__ ln_b,
                                              const float* __restrict__ M,
                                              const float* __restrict__ V,
                                              __half* __restrict__ qh,
                                              __half* __restrict__ kvh,
                                              unsigned char* __restrict__ fmap) {
    int gp = blockIdx.x * 256 + threadIdx.x;
    if (gp >= NPTS) return;
    int b = (gp >= NN) ? 1 : 0;
    int2 yx = ((const int2*)coors)[gp];
    int pix = (b << 18) + (yx.x << 9) + yx.y;

    const float* fr = feats + ((size_t)gp << 5);
    float x[32];
    #pragma unroll
    for (int k = 0; k < 8; ++k) ((float4*)x)[k] = ((const float4*)fr)[k];

    float s1 = 0.f, s2 = 0.f;
    #pragma unroll
    for (int j = 0; j < 32; ++j) { s1 += x[j]; s2 += x[j] * x[j]; }
    float mu   = s1 * (1.f / 32.f);
    float var  = s2 * (1.f / 32.f) - mu * mu;
    float rstd = rsqrtf(var + 1e-5f);
    #pragma unroll
    for (int j = 0; j < 32; ++j) x[j] = (x[j] - mu) * rstd * ln_w[j] + ln_b[j];

    const float4* M4 = (const float4*)M;   // M[j*32+c] == M4[j*8 + c/4]
    const float4* V4 = (const float4*)V;

    float4 a4[8];
    __half2 hbuf[16];

    // q' = x @ Mq + bq'  -> fp16 at pixel slot
    #pragma unroll
    for (int c = 0; c < 8; ++c) a4[c] = V4[c];
    #pragma unroll
    for (int j = 0; j < 32; ++j) {
        float xv = x[j];
        #pragma unroll
        for (int c = 0; c < 8; ++c) {
            float4 m = M4[j * 8 + c];
            a4[c].x += xv * m.x; a4[c].y += xv * m.y;
            a4[c].z += xv * m.z; a4[c].w += xv * m.w;
        }
    }
    #pragma unroll
    for (int c = 0; c < 8; ++c) {
        hbuf[2 * c]     = __floats2half2_rn(a4[c].x, a4[c].y);
        hbuf[2 * c + 1] = __floats2half2_rn(a4[c].z, a4[c].w);
    }
    {
        float4* qd = (float4*)(qh + ((size_t)pix << 5));
        #pragma unroll
        for (int k = 0; k < 4; ++k) qd[k] = ((float4*)hbuf)[k];
    }

    __half2 kvbuf[32];   // 128 B: k halves [0:16), v halves [16:32)

    // k' = x @ Mk + bk'  -> fp16
    #pragma unroll
    for (int c = 0; c < 8; ++c) a4[c] = V4[8 + c];
    #pragma unroll
    for (int j = 0; j < 32; ++j) {
        float xv = x[j];
        #pragma unroll
        for (int c = 0; c < 8; ++c) {
            float4 m = M4[256 + j * 8 + c];
            a4[c].x += xv * m.x; a4[c].y += xv * m.y;
            a4[c].z += xv * m.z; a4[c].w += xv * m.w;
        }
    }
    #pragma unroll
    for (int c = 0; c < 8; ++c) {
        kvbuf[2 * c]     = __floats2half2_rn(a4[c].x, a4[c].y);
        kvbuf[2 * c + 1] = __floats2half2_rn(a4[c].z, a4[c].w);
    }

    // v' = x @ Mv + bv'  -> fp16
    #pragma unroll
    for (int c = 0; c < 8; ++c) a4[c] = V4[16 + c];
    #pragma unroll
    for (int j = 0; j < 32; ++j) {
        float xv = x[j];
        #pragma unroll
        for (int c = 0; c < 8; ++c) {
            float4 m = M4[512 + j * 8 + c];
            a4[c].x += xv * m.x; a4[c].y += xv * m.y;
            a4[c].z += xv * m.z; a4[c].w += xv * m.w;
        }
    }
    #pragma unroll
    for (int c = 0; c < 8; ++c) {
        kvbuf[16 + 2 * c] = __floats2half2_rn(a4[c].x, a4[c].y);
        kvbuf[17 + 2 * c] = __floats2half2_rn(a4[c].z, a4[c].w);
    }

    float4* kd = (float4*)(kvh + ((size_t)pix << 6));
    #pragma unroll
    for (int k = 0; k < 8; ++k) kd[k] = ((float4*)kvbuf)[k];

    fmap[pix] = 1;
}

// ---------------- stage1b: compact occupied pixels into a pixel-ordered list ----------------
// Block = one 256-px window; ballot + one atomicAdd per block. Within-window order is
// pixel-ascending -> a stage2 block (256 consecutive list entries) covers ~2 adjacent
// window segments -> kv reads keep r0's L2 locality (r4 lesson: random point order
// -> FETCH 83 MB).
__global__ __launch_bounds__(256) void stage1b(const unsigned char* __restrict__ fmap,
                                               int* __restrict__ plist,
                                               int* __restrict__ pcnt) {
    __shared__ int woff[4];
    __shared__ int wbase;
    int tid = threadIdx.x;
    int pix = blockIdx.x * 256 + tid;
    bool occ = fmap[pix] != 0;
    unsigned long long mask = __ballot(occ);
    int lane = tid & 63, wv = tid >> 6;
    if (lane == 0) woff[wv] = __popcll(mask);
    __syncthreads();
    if (tid == 0) wbase = atomicAdd(pcnt, woff[0] + woff[1] + woff[2] + woff[3]);
    __syncthreads();
    if (occ) {
        int pre = 0;
        for (int i = 0; i < wv; ++i) pre += woff[i];
        plist[wbase + pre + __popcll(mask & ((1ull << lane) - 1ull))] = pix;
    }
}

// ---------------- stage2: attention + out-proj, one thread per point (pixel-ordered) ----------------
// r0's proven phase-A body (branchy valid-only loads, both heads, VGPR ~56) at 100%
// lane density via plist. Output (32 ch fp16, 64 B) overwrites the point's OWN q slot
// (q is only read by its owner -> safe in-place reuse; no extra workspace).
__global__ __launch_bounds__(256) void stage2(const int* __restrict__ plist,
                                              const unsigned char* __restrict__ fmap,
                                              __half* __restrict__ qh,
                                              const __half* __restrict__ kvh,
                                              const float* __restrict__ M,
                                              const float* __restrict__ V,
                                              const float* __restrict__ in_b,
                                              const float* __restrict__ out_b) {
    int t = blockIdx.x * 256 + threadIdx.x;
    if (t >= NPTS) return;
    int pixl = plist[t];
    int b = pixl >> 18;
    int p = pixl & (HWPIX - 1);
    int y = p >> 9, x = p & 511;

    const int DYC[9] = {0,-1,1,0,-1,1,0,-1,1};
    const int DXC[9] = {0,0,0,1,1,1,-1,-1,-1};

    float qf[32];
    {
        const float4* q4 = (const float4*)(qh + ((size_t)pixl << 5));
        float4 r0 = q4[0], r1 = q4[1], r2 = q4[2], r3 = q4[3];
        h8_to_f8(r0, qf); h8_to_f8(r1, qf + 8); h8_to_f8(r2, qf + 16); h8_to_f8(r3, qf + 24);
    }

    // 9 taps: validity is arithmetic + one independent flag byte each (no load chain)
    int np[9];
    bool nv[9];
    #pragma unroll
    for (int s = 0; s < 9; ++s) {
        int sy = y + DYC[s], sx = x + DXC[s];
        bool inb = (sy >= 0) & (sy < HH) & (sx >= 0) & (sx < WW);
        int npx = (b << 18) + (sy << 9) + sx;
        np[s] = npx;
        nv[s] = inb ? (fmap[npx] != 0) : false;
    }

    float eb0 = 0.f, eb1 = 0.f;
    #pragma unroll
    for (int c = 0; c < 16; ++c) {
        eb0 += qf[c]      * in_b[32 + c];
        eb1 += qf[16 + c] * in_b[48 + c];
    }

    float lg0[9], lg1[9];
    #pragma unroll
    for (int s = 0; s < 9; ++s) {
        float d0 = eb0, d1 = eb1;
        if (nv[s]) {
            const float4* kp = (const float4*)(kvh + ((size_t)np[s] << 6));
            float kf[32];
            h8_to_f8(kp[0], kf);      h8_to_f8(kp[1], kf + 8);
            h8_to_f8(kp[2], kf + 16); h8_to_f8(kp[3], kf + 24);
            #pragma unroll
            for (int c = 0; c < 16; ++c) {
                d0 += qf[c]      * kf[c];
                d1 += qf[16 + c] * kf[16 + c];
            }
        }
        lg0[s] = d0 * 0.25f;   // 1/sqrt(HD=16)
        lg1[s] = d1 * 0.25f;
    }
    float m0 = lg0[0], m1 = lg1[0];
    #pragma unroll
    for (int s = 1; s < 9; ++s) { m0 = fmaxf(m0, lg0[s]); m1 = fmaxf(m1, lg1[s]); }
    float l0 = 0.f, l1 = 0.f;
    #pragma unroll
    for (int s = 0; s < 9; ++s) {
        lg0[s] = __expf(lg0[s] - m0); l0 += lg0[s];
        lg1[s] = __expf(lg1[s] - m1); l1 += lg1[s];
    }

    float o[32];
    #pragma unroll
    for (int c = 0; c < 32; ++c) o[c] = 0.f;
    float wdy0 = 0.f, wdx0 = 0.f, woc0 = 0.f;
    float wdy1 = 0.f, wdx1 = 0.f, woc1 = 0.f;
    #pragma unroll
    for (int s = 0; s < 9; ++s) {
        if (nv[s]) {
            float w0 = lg0[s], w1 = lg1[s];
            const float4* vp = (const float4*)(kvh + ((size_t)np[s] << 6)) + 4;
            float vf[32];
            h8_to_f8(vp[0], vf);      h8_to_f8(vp[1], vf + 8);
            h8_to_f8(vp[2], vf + 16); h8_to_f8(vp[3], vf + 24);
            #pragma unroll
            for (int c = 0; c < 16; ++c) {
                o[c]      += w0 * vf[c];
                o[16 + c] += w1 * vf[16 + c];
            }
            wdy0 += w0 * (float)DYC[s]; wdx0 += w0 * (float)DXC[s]; woc0 += w0;
            wdy1 += w1 * (float)DYC[s]; wdx1 += w1 * (float)DXC[s]; woc1 += w1;
        }
    }
    float rl0 = 1.f / l0, rl1 = 1.f / l1;
    #pragma unroll
    for (int c = 0; c < 16; ++c) {
        o[c]      = (o[c]      + wdy0 * V[96 + c]      + wdx0 * V[128 + c]      + woc0 * V[160 + c])      * rl0 + in_b[64 + c];
        o[16 + c] = (o[16 + c] + wdy1 * V[96 + 16 + c] + wdx1 * V[128 + 16 + c] + woc1 * V[160 + 16 + c]) * rl1 + in_b[80 + c];
    }

    // out projection: all 32 channels, wave-uniform (scalarized) weights
    float acc[32];
    #pragma unroll
    for (int c = 0; c < 32; ++c) acc[c] = out_b[c];
    #pragma unroll
    for (int j = 0; j < 32; ++j) {
        float vj = o[j];
        #pragma unroll
        for (int c = 0; c < 32; ++c) acc[c] += vj * M[3072 + j * 32 + c];
    }

    // pack fp16 and overwrite own q slot (64 B)
    __half2 hbuf[16];
    #pragma unroll
    for (int c = 0; c < 16; ++c) hbuf[c] = __floats2half2_rn(acc[2 * c], acc[2 * c + 1]);
    float4* od = (float4*)(qh + ((size_t)pixl << 5));
    #pragma unroll
    for (int k = 0; k < 4; ++k) od[k] = ((float4*)hbuf)[k];
}

// ---------------- stage3: canvas write (pure BW) ----------------
// Thread per pixel: fmap coalesced; occupied -> read 64 B from qh (now holding the
// out-projection result) and write 32 floats strided-coalesced; else zeros.
__global__ __launch_bounds__(256) void stage3(const unsigned char* __restrict__ fmap,
                                              const __half* __restrict__ qh,
                                              float* __restrict__ out) {
    int pix = blockIdx.x * 256 + threadIdx.x;
    int b = pix >> 18;
    int p = pix & (HWPIX - 1);
    float* outb = out + (size_t)b * CC * HWPIX + p;
    if (fmap[pix] != 0) {
        const float4* o4 = (const float4*)(qh + ((size_t)pix << 5));
        float4 r0 = o4[0], r1 = o4[1], r2 = o4[2], r3 = o4[3];
        float of[32];
        h8_to_f8(r0, of); h8_to_f8(r1, of + 8); h8_to_f8(r2, of + 16); h8_to_f8(r3, of + 24);
        #pragma unroll
        for (int c = 0; c < 32; ++c) outb[c * HWPIX] = of[c];
    } else {
        #pragma unroll
        for (int c = 0; c < 32; ++c) outb[c * HWPIX] = 0.f;
    }
}

extern "C" void kernel_launch(void* const* d_in, const int* in_sizes, int n_in,
                              void* d_out, int out_size, void* d_ws, size_t ws_size,
                              hipStream_t stream) {
    const float* feats = (const float*)d_in[0];
    const int*   coors = (const int*)d_in[1];
    const float* ln_w  = (const float*)d_in[2];
    const float* ln_b  = (const float*)d_in[3];
    const float* wq    = (const float*)d_in[4];
    const float* bq    = (const float*)d_in[5];
    const float* wk    = (const float*)d_in[6];
    const float* bk    = (const float*)d_in[7];
    const float* wv    = (const float*)d_in[8];
    const float* bv    = (const float*)d_in[9];
    const float* pos_w = (const float*)d_in[10];
    const float* pos_b = (const float*)d_in[11];
    const float* in_w  = (const float*)d_in[12];
    const float* in_b  = (const float*)d_in[13];
    const float* out_w = (const float*)d_in[14];
    const float* out_b = (const float*)d_in[15];

    // workspace layout (pixel-dense)
    float*  M    = (float*)d_ws;                                        // 4096 floats
    float*  V    = M + 4096;                                            // 192 floats
    __half* qh   = (__half*)(V + 192);                                  // NPIX*32 halves (33.5 MB; q, then out)
    __half* kvh  = qh + (size_t)NPIX * 32;                              // NPIX*64 halves (67.1 MB)
    unsigned char* fmap = (unsigned char*)(kvh + (size_t)NPIX * 64);    // NPIX bytes (0.5 MB)
    int*    plist = (int*)(fmap + NPIX);                                // NPTS ints (0.96 MB)
    int*    pcnt  = plist + NPTS;                                       // 1 int
    size_t need = (4096 + 192) * 4 + (size_t)NPIX * 96 * 2 + (size_t)NPIX + (size_t)NPTS * 4 + 4;
    if (ws_size < need) {
        fprintf(stderr, "kernel_launch: ws too small: %zu < %zu\n", ws_size, need);
        return;
    }

    prep<<<81, 256, 0, stream>>>(wq, wk, wv, in_w, out_w, bq, bk, bv, in_b, pos_w, pos_b,
                                 M, V, (int*)fmap, pcnt);
    stage1<<<(NPTS + 255) / 256, 256, 0, stream>>>(feats, coors, ln_w, ln_b, M, V, qh, kvh, fmap);
    stage1b<<<NBLK, 256, 0, stream>>>(fmap, plist, pcnt);
    stage2<<<(NPTS + 255) / 256, 256, 0, stream>>>(plist, fmap, qh, kvh, M, V, in_b, out_b);
    stage3<<<NBLK, 256, 0, stream>>>(fmap, qh, (float*)d_out);
}

// Round 8
// 195.392 us; speedup vs baseline: 1.1872x; 1.1872x over previous
//
#include <hip/hip_runtime.h>
#include <hip/hip_fp16.h>
#include <cstdio>
#include <cstdint>

#define HH 512
#define WW 512
#define CC 32
#define BB 2
#define NN 120000
#define HWPIX (HH*WW)
#define NPTS (BB*NN)          // 240000 occupied points (all pixels distinct per batch)
#define NPIX (BB*HWPIX)       // 524288 pixels
#define NBLK (NPIX/256)       // 2048 pixel windows

__device__ __forceinline__ void h8_to_f8(float4 raw, float* o) {
    const __half2* h = (const __half2*)&raw;
    #pragma unroll
    for (int i = 0; i < 4; ++i) {
        float2 f = __half22float2(h[i]);
        o[2 * i] = f.x; o[2 * i + 1] = f.y;
    }
}

// ---------------- prep: compose weights + vecs + fill gpmap with -1 ----------------
// M layout (floats): [0:1024) MqT, [1024:2048) MkT, [2048:3072) MvT, [3072:4096) owT
// V layout (floats): [0:32) bq'=W1@bq+in_b[:32], [32:64) bk'=W2@bk, [64:96) bv'=W3@bv,
// [96:128) PWy, [128:160) PWx, [160:192) pb3=W3@pos_b
__global__ __launch_bounds__(256) void prep(const float* __restrict__ wq, const float* __restrict__ wk,
                          const float* __restrict__ wv, const float* __restrict__ in_w,
                          const float* __restrict__ out_w,
                          const float* __restrict__ bq, const float* __restrict__ bk,
                          const float* __restrict__ bv, const float* __restrict__ in_b,
                          const float* __restrict__ pos_w, const float* __restrict__ pos_b,
                          float* __restrict__ M, float* __restrict__ V, int* __restrict__ gpmap) {
    int blk = blockIdx.x;
    if (blk < 16) {
        int tid = blk * 256 + threadIdx.x;   // 0..4095
        int which = tid >> 10;
        int e = tid & 1023;
        int cp = e & 31;
        int j  = e >> 5;
        if (which < 3) {
            const float* w = (which == 0) ? wq : ((which == 1) ? wk : wv);
            const float* Wrow = in_w + (which * 32 + cp) * 32;
            float acc = 0.f;
            #pragma unroll
            for (int t = 0; t < 32; ++t) acc += Wrow[t] * w[t * 32 + j];
            M[which * 1024 + j * 32 + cp] = acc;
        } else {
            M[3 * 1024 + j * 32 + cp] = out_w[cp * 32 + j];
        }
    } else if (blk == 16) {
        int tid = threadIdx.x;
        if (tid < 32) {
            float a = 0.f, b = 0.f, c = 0.f;
            #pragma unroll
            for (int t = 0; t < 32; ++t) {
                a += in_w[tid * 32 + t] * bq[t];
                b += in_w[(32 + tid) * 32 + t] * bk[t];
                c += in_w[(64 + tid) * 32 + t] * bv[t];
            }
            V[tid]      = a + in_b[tid];
            V[32 + tid] = b;
            V[64 + tid] = c;
        } else if (tid < 128) {
            int grp = (tid - 32) >> 5;   // 0=PWy 1=PWx 2=pb3
            int cp  = tid & 31;
            float acc = 0.f;
            #pragma unroll
            for (int t = 0; t < 32; ++t) {
                float src = (grp == 0) ? pos_w[t * 2 + 0] : ((grp == 1) ? pos_w[t * 2 + 1] : pos_b[t]);
                acc += in_w[(64 + cp) * 32 + t] * src;
            }
            V[96 + grp * 32 + cp] = acc;
        }
    } else {
        // blocks 17..80: fill the 2 MB gpmap with -1 (524288 ints; 64 blocks x 256 thr x 32)
        int base = (blk - 17) * 8192 + threadIdx.x * 32;
        int4 m1 = {-1, -1, -1, -1};
        #pragma unroll
        for (int k = 0; k < 8; ++k) *(int4*)(gpmap + base + 4 * k) = m1;
    }
}

// ---------------- stage1: point-parallel LN + fused q/k/v linears (gp-indexed out) ----------------
// ALL big stores coalesced now: qg 64 B/thread, kvg 128 B/thread at gp slots.
// Only the 4 B gpmap[pix]=gp is scattered.
__global__ __launch_bounds__(256) void stage1(const float* __restrict__ feats,
                                              const int* __restrict__ coors,
                                              const float* __restrict__ ln_w,
                                              const float* __restrict__ ln_b,
                                              const float* __restrict__ M,
                                              const float* __restrict__ V,
                                              __half* __restrict__ qg,
                                              __half* __restrict__ kvg,
                                              int* __restrict__ gpmap) {
    int gp = blockIdx.x * 256 + threadIdx.x;
    if (gp >= NPTS) return;
    int b = (gp >= NN) ? 1 : 0;
    int2 yx = ((const int2*)coors)[gp];
    int pix = (b << 18) + (yx.x << 9) + yx.y;

    const float* fr = feats + ((size_t)gp << 5);
    float x[32];
    #pragma unroll
    for (int k = 0; k < 8; ++k) ((float4*)x)[k] = ((const float4*)fr)[k];

    float s1 = 0.f, s2 = 0.f;
    #pragma unroll
    for (int j = 0; j < 32; ++j) { s1 += x[j]; s2 += x[j] * x[j]; }
    float mu   = s1 * (1.f / 32.f);
    float var  = s2 * (1.f / 32.f) - mu * mu;
    float rstd = rsqrtf(var + 1e-5f);
    #pragma unroll
    for (int j = 0; j < 32; ++j) x[j] = (x[j] - mu) * rstd * ln_w[j] + ln_b[j];

    const float4* M4 = (const float4*)M;   // M[j*32+c] == M4[j*8 + c/4]
    const float4* V4 = (const float4*)V;

    float4 a4[8];
    __half2 hbuf[16];

    // q' = x @ Mq + bq'  -> fp16 at gp slot (coalesced)
    #pragma unroll
    for (int c = 0; c < 8; ++c) a4[c] = V4[c];
    #pragma unroll
    for (int j = 0; j < 32; ++j) {
        float xv = x[j];
        #pragma unroll
        for (int c = 0; c < 8; ++c) {
            float4 m = M4[j * 8 + c];
            a4[c].x += xv * m.x; a4[c].y += xv * m.y;
            a4[c].z += xv * m.z; a4[c].w += xv * m.w;
        }
    }
    #pragma unroll
    for (int c = 0; c < 8; ++c) {
        hbuf[2 * c]     = __floats2half2_rn(a4[c].x, a4[c].y);
        hbuf[2 * c + 1] = __floats2half2_rn(a4[c].z, a4[c].w);
    }
    {
        float4* qd = (float4*)(qg + ((size_t)gp << 5));
        #pragma unroll
        for (int k = 0; k < 4; ++k) qd[k] = ((float4*)hbuf)[k];
    }

    __half2 kvbuf[32];   // 128 B: k halves [0:16), v halves [16:32)

    // k' = x @ Mk + bk'  -> fp16
    #pragma unroll
    for (int c = 0; c < 8; ++c) a4[c] = V4[8 + c];
    #pragma unroll
    for (int j = 0; j < 32; ++j) {
        float xv = x[j];
        #pragma unroll
        for (int c = 0; c < 8; ++c) {
            float4 m = M4[256 + j * 8 + c];
            a4[c].x += xv * m.x; a4[c].y += xv * m.y;
            a4[c].z += xv * m.z; a4[c].w += xv * m.w;
        }
    }
    #pragma unroll
    for (int c = 0; c < 8; ++c) {
        kvbuf[2 * c]     = __floats2half2_rn(a4[c].x, a4[c].y);
        kvbuf[2 * c + 1] = __floats2half2_rn(a4[c].z, a4[c].w);
    }

    // v' = x @ Mv + bv'  -> fp16
    #pragma unroll
    for (int c = 0; c < 8; ++c) a4[c] = V4[16 + c];
    #pragma unroll
    for (int j = 0; j < 32; ++j) {
        float xv = x[j];
        #pragma unroll
        for (int c = 0; c < 8; ++c) {
            float4 m = M4[512 + j * 8 + c];
            a4[c].x += xv * m.x; a4[c].y += xv * m.y;
            a4[c].z += xv * m.z; a4[c].w += xv * m.w;
        }
    }
    #pragma unroll
    for (int c = 0; c < 8; ++c) {
        kvbuf[16 + 2 * c] = __floats2half2_rn(a4[c].x, a4[c].y);
        kvbuf[17 + 2 * c] = __floats2half2_rn(a4[c].z, a4[c].w);
    }

    float4* kd = (float4*)(kvg + ((size_t)gp << 6));
    #pragma unroll
    for (int k = 0; k < 8; ++k) kd[k] = ((float4*)kvbuf)[k];

    gpmap[pix] = gp;
}

// ---------------- stage23: fused attention + out-proj + canvas write (r0 structure) ----------------
// Identical control flow to the proven 56 µs kernel; only the indirection changed:
// fmap byte -> gpmap dword (same tap chain depth: map load then kv load), q/kv at
// gp slots. Windowed blocks + XCD swizzle + fused phase-B canvas write retained.
__global__ __launch_bounds__(256) void stage23(const int* __restrict__ gpmap,
                                               const __half* __restrict__ qg,
                                               const __half* __restrict__ kvg,
                                               const float* __restrict__ M,
                                               const float* __restrict__ V,
                                               const float* __restrict__ in_b,
                                               const float* __restrict__ out_b,
                                               float* __restrict__ out) {
    __shared__ __half2 lso[256 * 17];   // 17 half2 (68 B) stride per point
    __shared__ int lsp[256];            // slot -> pixel-in-window
    __shared__ int lsg[256];            // slot -> gp
    __shared__ int woff[4];

    int w = (blockIdx.x & 7) * 256 + (blockIdx.x >> 3);   // XCD-swizzled window index
    int tid = threadIdx.x;
    int pix = w * 256 + tid;

    int mygp = gpmap[pix];              // coalesced 1 KB/wave
    bool occ = mygp >= 0;
    unsigned long long mask = __ballot(occ);
    int lane = tid & 63, wvi = tid >> 6;
    if (lane == 0) woff[wvi] = __popcll(mask);
    __syncthreads();
    int pre = 0;
    for (int ww = 0; ww < wvi; ++ww) pre += woff[ww];
    int cnt = woff[0] + woff[1] + woff[2] + woff[3];
    int slot = -1;
    if (occ) {
        slot = pre + __popcll(mask & ((1ull << lane) - 1ull));
        lsp[slot] = tid;
        lsg[slot] = mygp;
    }
    __syncthreads();

    const int DYC[9] = {0,-1,1,0,-1,1,0,-1,1};
    const int DXC[9] = {0,0,0,1,1,1,-1,-1,-1};

    // ---- phase A: attention, one thread per occupied pixel ----
    if (tid < cnt) {
        int pixl = w * 256 + lsp[tid];
        int gpl  = lsg[tid];
        int b = pixl >> 18;
        int p = pixl & (HWPIX - 1);
        int y = p >> 9, x = p & 511;

        float qf[32];
        {
            const float4* q4 = (const float4*)(qg + ((size_t)gpl << 5));
            float4 r0 = q4[0], r1 = q4[1], r2 = q4[2], r3 = q4[3];
            h8_to_f8(r0, qf); h8_to_f8(r1, qf + 8); h8_to_f8(r2, qf + 16); h8_to_f8(r3, qf + 24);
        }

        // 9 taps: validity + kv index from one gpmap dword each (independent loads)
        int ng[9];
        #pragma unroll
        for (int s = 0; s < 9; ++s) {
            int sy = y + DYC[s], sx = x + DXC[s];
            bool inb = (sy >= 0) & (sy < HH) & (sx >= 0) & (sx < WW);
            int npx = (b << 18) + (sy << 9) + sx;
            ng[s] = inb ? gpmap[npx] : -1;
        }

        float eb0 = 0.f, eb1 = 0.f;
        #pragma unroll
        for (int c = 0; c < 16; ++c) {
            eb0 += qf[c]      * in_b[32 + c];
            eb1 += qf[16 + c] * in_b[48 + c];
        }

        float lg0[9], lg1[9];
        #pragma unroll
        for (int s = 0; s < 9; ++s) {
            float d0 = eb0, d1 = eb1;
            if (ng[s] >= 0) {
                const float4* kp = (const float4*)(kvg + ((size_t)ng[s] << 6));
                float kf[32];
                h8_to_f8(kp[0], kf);      h8_to_f8(kp[1], kf + 8);
                h8_to_f8(kp[2], kf + 16); h8_to_f8(kp[3], kf + 24);
                #pragma unroll
                for (int c = 0; c < 16; ++c) {
                    d0 += qf[c]      * kf[c];
                    d1 += qf[16 + c] * kf[16 + c];
                }
            }
            lg0[s] = d0 * 0.25f;   // 1/sqrt(HD=16)
            lg1[s] = d1 * 0.25f;
        }
        float m0 = lg0[0], m1 = lg1[0];
        #pragma unroll
        for (int s = 1; s < 9; ++s) { m0 = fmaxf(m0, lg0[s]); m1 = fmaxf(m1, lg1[s]); }
        float l0 = 0.f, l1 = 0.f;
        #pragma unroll
        for (int s = 0; s < 9; ++s) {
            lg0[s] = __expf(lg0[s] - m0); l0 += lg0[s];
            lg1[s] = __expf(lg1[s] - m1); l1 += lg1[s];
        }

        float o[32];
        #pragma unroll
        for (int c = 0; c < 32; ++c) o[c] = 0.f;
        float wdy0 = 0.f, wdx0 = 0.f, woc0 = 0.f;
        float wdy1 = 0.f, wdx1 = 0.f, woc1 = 0.f;
        #pragma unroll
        for (int s = 0; s < 9; ++s) {
            if (ng[s] >= 0) {
                float w0 = lg0[s], w1 = lg1[s];
                const float4* vp = (const float4*)(kvg + ((size_t)ng[s] << 6)) + 4;
                float vf[32];
                h8_to_f8(vp[0], vf);      h8_to_f8(vp[1], vf + 8);
                h8_to_f8(vp[2], vf + 16); h8_to_f8(vp[3], vf + 24);
                #pragma unroll
                for (int c = 0; c < 16; ++c) {
                    o[c]      += w0 * vf[c];
                    o[16 + c] += w1 * vf[16 + c];
                }
                wdy0 += w0 * (float)DYC[s]; wdx0 += w0 * (float)DXC[s]; woc0 += w0;
                wdy1 += w1 * (float)DYC[s]; wdx1 += w1 * (float)DXC[s]; woc1 += w1;
            }
        }
        float rl0 = 1.f / l0, rl1 = 1.f / l1;
        #pragma unroll
        for (int c = 0; c < 16; ++c) {
            o[c]      = (o[c]      + wdy0 * V[96 + c]      + wdx0 * V[128 + c]      + woc0 * V[160 + c])      * rl0 + in_b[64 + c];
            o[16 + c] = (o[16 + c] + wdy1 * V[96 + 16 + c] + wdx1 * V[128 + 16 + c] + woc1 * V[160 + 16 + c]) * rl1 + in_b[80 + c];
        }

        // out projection: all 32 channels, wave-uniform (scalarized) weights
        float acc[32];
        #pragma unroll
        for (int c = 0; c < 32; ++c) acc[c] = out_b[c];
        #pragma unroll
        for (int j = 0; j < 32; ++j) {
            float vj = o[j];
            #pragma unroll
            for (int c = 0; c < 32; ++c) acc[c] += vj * M[3072 + j * 32 + c];
        }

        // pack fp16 into LDS row (stride 17 half2)
        __half2* lrow = lso + tid * 17;
        #pragma unroll
        for (int c = 0; c < 16; ++c) lrow[c] = __floats2half2_rn(acc[2 * c], acc[2 * c + 1]);
    }
    __syncthreads();

    // ---- phase B: canvas write (all 256 threads; 256 B contiguous per wave-instr) ----
    int b = pix >> 18;
    int p = pix & (HWPIX - 1);
    float* outb = out + (size_t)b * CC * HWPIX + p;
    if (occ) {
        const __half2* lrow = lso + slot * 17;
        #pragma unroll
        for (int c2 = 0; c2 < 16; ++c2) {
            float2 f = __half22float2(lrow[c2]);
            outb[(2 * c2) * HWPIX]     = f.x;
            outb[(2 * c2 + 1) * HWPIX] = f.y;
        }
    } else {
        #pragma unroll
        for (int cc = 0; cc < 32; ++cc) outb[cc * HWPIX] = 0.f;
    }
}

extern "C" void kernel_launch(void* const* d_in, const int* in_sizes, int n_in,
                              void* d_out, int out_size, void* d_ws, size_t ws_size,
                              hipStream_t stream) {
    const float* feats = (const float*)d_in[0];
    const int*   coors = (const int*)d_in[1];
    const float* ln_w  = (const float*)d_in[2];
    const float* ln_b  = (const float*)d_in[3];
    const float* wq    = (const float*)d_in[4];
    const float* bq    = (const float*)d_in[5];
    const float* wk    = (const float*)d_in[6];
    const float* bk    = (const float*)d_in[7];
    const float* wv    = (const float*)d_in[8];
    const float* bv    = (const float*)d_in[9];
    const float* pos_w = (const float*)d_in[10];
    const float* pos_b = (const float*)d_in[11];
    const float* in_w  = (const float*)d_in[12];
    const float* in_b  = (const float*)d_in[13];
    const float* out_w = (const float*)d_in[14];
    const float* out_b = (const float*)d_in[15];

    // workspace layout (gp-indexed; total ~48 MB vs 101 MB pixel-dense)
    float*  M    = (float*)d_ws;                                        // 4096 floats
    float*  V    = M + 4096;                                            // 192 floats
    __half* qg   = (__half*)(V + 192);                                  // NPTS*32 halves (15.4 MB)
    __half* kvg  = qg + (size_t)NPTS * 32;                              // NPTS*64 halves (30.7 MB)
    int*   gpmap = (int*)(kvg + (size_t)NPTS * 64);                     // NPIX ints (2.1 MB)
    size_t need = (4096 + 192) * 4 + (size_t)NPTS * 96 * 2 + (size_t)NPIX * 4;
    if (ws_size < need) {
        fprintf(stderr, "kernel_launch: ws too small: %zu < %zu\n", ws_size, need);
        return;
    }

    prep<<<81, 256, 0, stream>>>(wq, wk, wv, in_w, out_w, bq, bk, bv, in_b, pos_w, pos_b,
                                 M, V, gpmap);
    stage1<<<(NPTS + 255) / 256, 256, 0, stream>>>(feats, coors, ln_w, ln_b, M, V, qg, kvg, gpmap);
    stage23<<<NBLK, 256, 0, stream>>>(gpmap, qg, kvg, M, V, in_b, out_b, (float*)d_out);
}